// Round 6
// baseline (346.735 us; speedup 1.0000x reference)
//
#include <hip/hip_runtime.h>

#define HID 32
#define MIN_WEIGHT -100000.0f

// ---------------------------------------------------------------------------
// Node-stage kernel, column-lane layout. Block = 256 threads = 4 waves.
// Each wave independently owns 8 nodes: lane = (h, c) with h = lane>>5 the
// node parity, c = lane&31 the output column. Pair p covers nodes {2p+h}.
//   layer 1 : acc[p] += row_p[j] * W[j][c]
//             - W[j][c]: coalesced 128 B line, L1-resident (W <= 32 KB), no
//               scalar path, no K$ misses on the critical chain
//             - row_p[j]: same-address broadcast float4 per half-wave; 4
//               independent gathers in flight
//   exchange: g -> wave-private LDS slice [8][33] (bank (node+c)%32, 2-way)
//   proj    : pj[p] += g[node][j] * P[j][c]  (ds_read broadcast + L1 line)
// No __syncthreads anywhere; tiny VGPR footprint -> high occupancy.
template <int ROW, bool TWO>
__global__ __launch_bounds__(256) void nodek(
    const float* __restrict__ emb, const int* __restrict__ n_map,
    const int* __restrict__ sel, const float* __restrict__ W,
    const float* __restrict__ P0, const float* __restrict__ P1,
    float* __restrict__ o0, float* __restrict__ o1, int n) {
    __shared__ float gl[32 * 33];  // 4.2 KB; wave w uses rows [w*8, w*8+8)

    const int tid = threadIdx.x;
    const int w = tid >> 6;    // wave id 0..3
    const int lane = tid & 63;
    const int h = lane >> 5;   // node parity in pair
    const int c = lane & 31;   // output column

    int nd[4];
    const float* rp[4];
#pragma unroll
    for (int p = 0; p < 4; ++p) {
        int node = blockIdx.x * 32 + w * 8 + p * 2 + h;
        nd[p] = node;
        int cn = node < n ? node : n - 1;  // clamp, keep lanes active
        int local = sel ? sel[cn] : cn;
        rp[p] = emb + (size_t)n_map[local] * ROW;
    }

    float acc[4] = {0.f, 0.f, 0.f, 0.f};
#pragma unroll 2
    for (int j0 = 0; j0 < ROW; j0 += 4) {
        float4 rr[4];
#pragma unroll
        for (int p = 0; p < 4; ++p) rr[p] = *(const float4*)(rp[p] + j0);
#pragma unroll
        for (int jj = 0; jj < 4; ++jj) {
            float wv = W[(size_t)(j0 + jj) * HID + c];  // coalesced, L1-hot
            const float* rf = (const float*)&rr[0];
            acc[0] = fmaf(((const float*)&rr[0])[jj], wv, acc[0]);
            acc[1] = fmaf(((const float*)&rr[1])[jj], wv, acc[1]);
            acc[2] = fmaf(((const float*)&rr[2])[jj], wv, acc[2]);
            acc[3] = fmaf(((const float*)&rr[3])[jj], wv, acc[3]);
            (void)rf;
        }
    }

    // relu -> wave-private LDS slice; banks (node+c)%32: 2-way = free
#pragma unroll
    for (int p = 0; p < 4; ++p)
        gl[(w * 8 + p * 2 + h) * 33 + c] = fmaxf(acc[p], 0.f);

    // projections; g via ds_read broadcast (2 addrs/instr), P via L1 line
    float pj0[4] = {0.f, 0.f, 0.f, 0.f};
    float pj1[4] = {0.f, 0.f, 0.f, 0.f};
    const int gb = w * 8 * 33;
#pragma unroll 4
    for (int j = 0; j < HID; ++j) {
        float wa = P0[(size_t)j * HID + c];
        float wb = TWO ? P1[(size_t)j * HID + c] : 0.f;
#pragma unroll
        for (int p = 0; p < 4; ++p) {
            float gv = gl[gb + (p * 2 + h) * 33 + j];
            pj0[p] = fmaf(gv, wa, pj0[p]);
            if (TWO) pj1[p] = fmaf(gv, wb, pj1[p]);
        }
    }

    // stores: per half-wave 128 B contiguous
#pragma unroll
    for (int p = 0; p < 4; ++p) {
        if (nd[p] < n) {
            o0[(size_t)nd[p] * HID + c] = pj0[p];
            if (TWO) o1[(size_t)nd[p] * HID + c] = pj1[p];
        }
    }
}

// ---------------------------------------------------------------------------
// Per-edge: att = relu(SA[src] + DB[dst] + t2[batch] + be1) @ We2 + be2
// Writes att to its own slab and MIN_WEIGHT to the other slab (the two hop
// index sets partition [0,E), so the two edge launches cover all of d_out).
__global__ __launch_bounds__(256) void edge_kernel(
    const int* __restrict__ hop_idx, int n_e, const int* __restrict__ src,
    const int* __restrict__ dst, const int* __restrict__ e_batch,
    const float* __restrict__ SA, const float* __restrict__ DB,
    const float* __restrict__ t2, const float* __restrict__ be1,
    const float* __restrict__ We2, const float* __restrict__ be2,
    float* __restrict__ out_att, float* __restrict__ out_min) {
    int i = blockIdx.x * blockDim.x + threadIdx.x;
    if (i >= n_e) return;
    int e = hop_idx[i];
    const float* sv = SA + (size_t)src[e] * HID;
    const float* dv = DB + (size_t)dst[e] * HID;
    const float* tv = t2 + (size_t)e_batch[e] * HID;
    float att = be2[0];
#pragma unroll
    for (int k = 0; k < HID; k += 4) {
        float4 s4 = *(const float4*)(sv + k);
        float4 d4 = *(const float4*)(dv + k);
        float4 t4 = *(const float4*)(tv + k);
        float h;
        h = fmaxf(s4.x + d4.x + t4.x + be1[k + 0], 0.f); att = fmaf(h, We2[k + 0], att);
        h = fmaxf(s4.y + d4.y + t4.y + be1[k + 1], 0.f); att = fmaf(h, We2[k + 1], att);
        h = fmaxf(s4.z + d4.z + t4.z + be1[k + 2], 0.f); att = fmaf(h, We2[k + 2], att);
        h = fmaxf(s4.w + d4.w + t4.w + be1[k + 3], 0.f); att = fmaf(h, We2[k + 3], att);
    }
    out_att[e] = att;
    out_min[e] = MIN_WEIGHT;
}

// ---------------------------------------------------------------------------
extern "C" void kernel_launch(void* const* d_in, const int* in_sizes, int n_in,
                              void* d_out, int out_size, void* d_ws, size_t ws_size,
                              hipStream_t stream) {
    const float* emb0 = (const float*)d_in[0];
    const float* emb1 = (const float*)d_in[1];
    const float* emb2 = (const float*)d_in[2];
    const int* n_map = (const int*)d_in[3];
    const int* src = (const int*)d_in[4];
    const int* dst = (const int*)d_in[5];
    const int* e_batch = (const int*)d_in[6];
    const int* offset_node = (const int*)d_in[7];
    const int* one_hop = (const int*)d_in[8];
    const int* two_hop = (const int*)d_in[9];
    const float* W0 = (const float*)d_in[10];
    const float* W1 = (const float*)d_in[11];
    const float* W2 = (const float*)d_in[12];
    const float* We1 = (const float*)d_in[13];
    const float* be1 = (const float*)d_in[14];
    const float* We2 = (const float*)d_in[15];
    const float* be2 = (const float*)d_in[16];

    const int n_nodes = in_sizes[3];
    const int E = in_sizes[4];
    const int batch = in_sizes[7];
    const int H1 = in_sizes[8];  // one-hop edge count
    const int H2 = in_sizes[9];  // two-hop edge count

    float* out = (float*)d_out;

    const float* A = We1;             // rows 0..31   (multiplies s)
    const float* B = We1 + 32 * HID;  // rows 32..63  (multiplies d)
    const float* T = We1 + 64 * HID;  // rows 64..95  (multiplies t)

    // workspace layout: a0 | a1 | b1 | b2 | t2
    float* a0 = (float*)d_ws;
    float* a1 = a0 + (size_t)n_nodes * HID;
    float* b1 = a1 + (size_t)n_nodes * HID;
    float* b2 = b1 + (size_t)n_nodes * HID;
    float* t2 = b2 + (size_t)n_nodes * HID;

    const int nblk = (n_nodes + 31) / 32;
    // a0 = relu(emb0@W0)@A
    nodek<128, false><<<nblk, 256, 0, stream>>>(
        emb0, n_map, nullptr, W0, A, nullptr, a0, nullptr, n_nodes);
    // a1 = relu(emb1@W1)@A ; b1 = relu(emb1@W1)@B
    nodek<256, true><<<nblk, 256, 0, stream>>>(
        emb1, n_map, nullptr, W1, A, B, a1, b1, n_nodes);
    // b2 = relu(emb2@W2)@B
    nodek<64, false><<<nblk, 256, 0, stream>>>(
        emb2, n_map, nullptr, W2, B, nullptr, b2, nullptr, n_nodes);
    // t2 = relu(emb2[n_map[offset_node]]@W2)@T
    nodek<64, false><<<(batch + 31) / 32, 256, 0, stream>>>(
        emb2, n_map, offset_node, W2, T, nullptr, t2, nullptr, batch);

    // one-hop edges: att -> slab 1, MIN -> slab 0 (src via W1@A, dst via W2@B)
    edge_kernel<<<(H1 + 255) / 256, 256, 0, stream>>>(
        one_hop, H1, src, dst, e_batch, a1, b2, t2, be1, We2, be2,
        out + (size_t)E, out);
    // two-hop edges: att -> slab 0, MIN -> slab 1 (src via W0@A, dst via W1@B)
    edge_kernel<<<(H2 + 255) / 256, 256, 0, stream>>>(
        two_hop, H2, src, dst, e_batch, a0, b1, t2, be1, We2, be2,
        out, out + (size_t)E);
}

// Round 7
// 235.334 us; speedup vs baseline: 1.4734x; 1.4734x over previous
//
#include <hip/hip_runtime.h>

#define HID 32
#define MIN_WEIGHT -100000.0f

// ---------------------------------------------------------------------------
// async global->LDS, 16B per lane, wave-uniform LDS base (+lane*16 implicit)
__device__ __forceinline__ void gld16(const float* g, float* l) {
    __builtin_amdgcn_global_load_lds(
        (const __attribute__((address_space(1))) unsigned int*)g,
        (__attribute__((address_space(3))) unsigned int*)l, 16, 0, 0);
}

// ---------------------------------------------------------------------------
// Node-stage kernel. Block = 256 threads = 4 waves, 32 nodes per block.
// Wave w owns nodes [w*8, w*8+8) END-TO-END: it stages exactly those 8 rows
// into LDS via global_load_lds (8KB in flight), waits vmcnt(0), computes.
// No __syncthreads anywhere; LDS regions are wave-private.
//   layer 1: lane=(h,c): acc[p] += lds_row[2p+h][j] * W[j][c]
//            row value: ds_read_b128 broadcast; W: coalesced 128B, L1-hot
//   proj   : g -> gl[node][33] (wave-private exchange), pj += g*P[j][c]
template <int ROW, bool TWO>
__global__ __launch_bounds__(256) void nodek(
    const float* __restrict__ emb, const int* __restrict__ n_map,
    const int* __restrict__ sel, const float* __restrict__ W,
    const float* __restrict__ P0, const float* __restrict__ P1,
    float* __restrict__ o0, float* __restrict__ o1, int n) {
    constexpr int TILE = 32;        // nodes per block
    constexpr int LPR = ROW / 4;    // lanes covering one row (16B chunks)
    constexpr int RPI = 64 / LPR;   // rows staged per instruction
    constexpr int NI = TILE / RPI;  // stage instructions per block
    constexpr int IPW = NI / 4;     // stage instructions per wave

    __shared__ float rows[TILE * ROW];  // staged embedding rows
    __shared__ float gl[TILE * 33];     // g exchange, pad 33

    const int tid = threadIdx.x;
    const int w = tid >> 6;
    const int lane = tid & 63;
    const int base = blockIdx.x * TILE;

    // ---- stage my wave's 8 rows (rows w*8 .. w*8+8) ------------------------
    const int sub = lane / LPR;    // row within instruction
    const int chunk = lane % LPR;  // 16B chunk within row
#pragma unroll
    for (int i = 0; i < IPW; ++i) {
        const int ii = w * IPW + i;          // global instr index (uniform)
        const int r = ii * RPI + sub;        // my row
        int node = base + r;
        int cn = node < n ? node : n - 1;    // clamp, keep lanes active
        int local = sel ? sel[cn] : cn;
        int gn = n_map[local];
        const float* src = emb + (size_t)gn * ROW + chunk * 4;
        gld16(src, &rows[ii * RPI * ROW]);   // wave-uniform LDS base
    }
    asm volatile("s_waitcnt vmcnt(0)" ::: "memory");

    // ---- layer 1: 8 nodes as 4 pairs x parity h ---------------------------
    const int h = lane >> 5;
    const int c = lane & 31;

    float acc[4] = {0.f, 0.f, 0.f, 0.f};
    const float* wcol = W + c;
#pragma unroll 2
    for (int j0 = 0; j0 < ROW; j0 += 4) {
        float4 rr[4];
#pragma unroll
        for (int p = 0; p < 4; ++p)
            rr[p] = *(const float4*)&rows[(w * 8 + p * 2 + h) * ROW + j0];
#pragma unroll
        for (int jj = 0; jj < 4; ++jj) {
            float wv = wcol[(size_t)(j0 + jj) * HID];  // 128B line, L1-hot
            acc[0] = fmaf(((const float*)&rr[0])[jj], wv, acc[0]);
            acc[1] = fmaf(((const float*)&rr[1])[jj], wv, acc[1]);
            acc[2] = fmaf(((const float*)&rr[2])[jj], wv, acc[2]);
            acc[3] = fmaf(((const float*)&rr[3])[jj], wv, acc[3]);
        }
    }

    // relu -> wave-private exchange (banks (node+c)%32: 2-way = free)
#pragma unroll
    for (int p = 0; p < 4; ++p)
        gl[(w * 8 + p * 2 + h) * 33 + c] = fmaxf(acc[p], 0.f);

    // ---- projections ------------------------------------------------------
    float pj0[4] = {0.f, 0.f, 0.f, 0.f};
    float pj1[4] = {0.f, 0.f, 0.f, 0.f};
    const int gb = w * 8 * 33;
#pragma unroll 4
    for (int j = 0; j < HID; ++j) {
        float wa = P0[(size_t)j * HID + c];
        float wb = TWO ? P1[(size_t)j * HID + c] : 0.f;
#pragma unroll
        for (int p = 0; p < 4; ++p) {
            float gv = gl[gb + (p * 2 + h) * 33 + j];  // broadcast
            pj0[p] = fmaf(gv, wa, pj0[p]);
            if (TWO) pj1[p] = fmaf(gv, wb, pj1[p]);
        }
    }

    // stores: per half-wave 128B contiguous
#pragma unroll
    for (int p = 0; p < 4; ++p) {
        int node = base + w * 8 + p * 2 + h;
        if (node < n) {
            o0[(size_t)node * HID + c] = pj0[p];
            if (TWO) o1[(size_t)node * HID + c] = pj1[p];
        }
    }
}

// ---------------------------------------------------------------------------
// Per-edge: att = relu(SA[src] + DB[dst] + t2[batch] + be1) @ We2 + be2
// Writes att to its own slab and MIN_WEIGHT to the other slab (the two hop
// index sets partition [0,E), so the two edge launches cover all of d_out).
__global__ __launch_bounds__(256) void edge_kernel(
    const int* __restrict__ hop_idx, int n_e, const int* __restrict__ src,
    const int* __restrict__ dst, const int* __restrict__ e_batch,
    const float* __restrict__ SA, const float* __restrict__ DB,
    const float* __restrict__ t2, const float* __restrict__ be1,
    const float* __restrict__ We2, const float* __restrict__ be2,
    float* __restrict__ out_att, float* __restrict__ out_min) {
    int i = blockIdx.x * blockDim.x + threadIdx.x;
    if (i >= n_e) return;
    int e = hop_idx[i];
    const float* sv = SA + (size_t)src[e] * HID;
    const float* dv = DB + (size_t)dst[e] * HID;
    const float* tv = t2 + (size_t)e_batch[e] * HID;
    float att = be2[0];
#pragma unroll
    for (int k = 0; k < HID; k += 4) {
        float4 s4 = *(const float4*)(sv + k);
        float4 d4 = *(const float4*)(dv + k);
        float4 t4 = *(const float4*)(tv + k);
        float h;
        h = fmaxf(s4.x + d4.x + t4.x + be1[k + 0], 0.f); att = fmaf(h, We2[k + 0], att);
        h = fmaxf(s4.y + d4.y + t4.y + be1[k + 1], 0.f); att = fmaf(h, We2[k + 1], att);
        h = fmaxf(s4.z + d4.z + t4.z + be1[k + 2], 0.f); att = fmaf(h, We2[k + 2], att);
        h = fmaxf(s4.w + d4.w + t4.w + be1[k + 3], 0.f); att = fmaf(h, We2[k + 3], att);
    }
    out_att[e] = att;
    out_min[e] = MIN_WEIGHT;
}

// ---------------------------------------------------------------------------
extern "C" void kernel_launch(void* const* d_in, const int* in_sizes, int n_in,
                              void* d_out, int out_size, void* d_ws, size_t ws_size,
                              hipStream_t stream) {
    const float* emb0 = (const float*)d_in[0];
    const float* emb1 = (const float*)d_in[1];
    const float* emb2 = (const float*)d_in[2];
    const int* n_map = (const int*)d_in[3];
    const int* src = (const int*)d_in[4];
    const int* dst = (const int*)d_in[5];
    const int* e_batch = (const int*)d_in[6];
    const int* offset_node = (const int*)d_in[7];
    const int* one_hop = (const int*)d_in[8];
    const int* two_hop = (const int*)d_in[9];
    const float* W0 = (const float*)d_in[10];
    const float* W1 = (const float*)d_in[11];
    const float* W2 = (const float*)d_in[12];
    const float* We1 = (const float*)d_in[13];
    const float* be1 = (const float*)d_in[14];
    const float* We2 = (const float*)d_in[15];
    const float* be2 = (const float*)d_in[16];

    const int n_nodes = in_sizes[3];
    const int E = in_sizes[4];
    const int batch = in_sizes[7];
    const int H1 = in_sizes[8];  // one-hop edge count
    const int H2 = in_sizes[9];  // two-hop edge count

    float* out = (float*)d_out;

    const float* A = We1;             // rows 0..31   (multiplies s)
    const float* B = We1 + 32 * HID;  // rows 32..63  (multiplies d)
    const float* T = We1 + 64 * HID;  // rows 64..95  (multiplies t)

    // workspace layout: a0 | a1 | b1 | b2 | t2
    float* a0 = (float*)d_ws;
    float* a1 = a0 + (size_t)n_nodes * HID;
    float* b1 = a1 + (size_t)n_nodes * HID;
    float* b2 = b1 + (size_t)n_nodes * HID;
    float* t2 = b2 + (size_t)n_nodes * HID;

    const int nblk = (n_nodes + 31) / 32;
    // a0 = relu(emb0@W0)@A
    nodek<128, false><<<nblk, 256, 0, stream>>>(
        emb0, n_map, nullptr, W0, A, nullptr, a0, nullptr, n_nodes);
    // a1 = relu(emb1@W1)@A ; b1 = relu(emb1@W1)@B
    nodek<256, true><<<nblk, 256, 0, stream>>>(
        emb1, n_map, nullptr, W1, A, B, a1, b1, n_nodes);
    // b2 = relu(emb2@W2)@B
    nodek<64, false><<<nblk, 256, 0, stream>>>(
        emb2, n_map, nullptr, W2, B, nullptr, b2, nullptr, n_nodes);
    // t2 = relu(emb2[n_map[offset_node]]@W2)@T
    nodek<64, false><<<(batch + 31) / 32, 256, 0, stream>>>(
        emb2, n_map, offset_node, W2, T, nullptr, t2, nullptr, batch);

    // one-hop edges: att -> slab 1, MIN -> slab 0 (src via W1@A, dst via W2@B)
    edge_kernel<<<(H1 + 255) / 256, 256, 0, stream>>>(
        one_hop, H1, src, dst, e_batch, a1, b2, t2, be1, We2, be2,
        out + (size_t)E, out);
    // two-hop edges: att -> slab 0, MIN -> slab 1 (src via W0@A, dst via W1@B)
    edge_kernel<<<(H2 + 255) / 256, 256, 0, stream>>>(
        two_hop, H2, src, dst, e_batch, a0, b1, t2, be1, We2, be2,
        out, out + (size_t)E);
}